// Round 21
// baseline (135.449 us; speedup 1.0000x reference)
//
#include <hip/hip_runtime.h>

#define BATCH 262144

typedef __attribute__((ext_vector_type(8))) short short8;
typedef __attribute__((ext_vector_type(4))) float f32x4;

static __device__ __forceinline__ unsigned cvtpk(float lo, float hi) {
    unsigned r;
    asm("v_cvt_pk_bf16_f32 %0, %1, %2" : "=v"(r) : "v"(lo), "v"(hi));
    return r;
}
static __device__ __forceinline__ float b2f(short s) {
    return __uint_as_float(((unsigned)(unsigned short)s) << 16);
}
static __device__ __forceinline__ float sigm(float x) { return 1.0f / (1.0f + __expf(-x)); }
static __device__ __forceinline__ float tanh_f(float x) { return 1.0f - 2.0f / (__expf(2.0f * x) + 1.0f); }

// LDS serves a wave's DS ops in program order; compiler-only barrier (R15).
#define WAVE_FENCE() asm volatile("" ::: "memory")

// XOR swizzle on 16B slots within a row (R4/R10-validated, <=2-way aliasing).
static __device__ __forceinline__ int sw128(int row, int cb) { return row * 128 + (cb ^ ((row & 7) << 4)); }
static __device__ __forceinline__ int sw256(int row, int cb) { return row * 256 + (cb ^ ((row & 7) << 4)); }

// Weight LDS (swizzled): w1 @0 [64][128]s256, w2 @16384 [64][64]s128,
// wih @24576 [192][64]s128, whh @49152 [192][64]s128, lw1 @73728 [64][128]s256
#define WLDS_BYTES 90112
#define NCHUNK (WLDS_BYTES / 16)

// R21: M=32 per wave — TWO 16-row tiles (A,B) share every weight B-fragment.
// 384 threads = 6 waves; LDS 90112 + 6*12288 = 163840 B = full pool, 1 blk/CU.
// Rows/pass unchanged (6x32 = 12x16); weight ds_reads HALVE; the two tiles'
// MFMAs are independent -> 2x intra-stage ILP. Budget at <=2 waves/SIMD is
// 256 regs/wave vs est. peak ~190-220 -> first variant with real reg slack.
// Weights converted f32->bf16 during staging (R20). Persistent grid=256.
__global__ __launch_bounds__(384) void tgn_kernel(
    const int* __restrict__ pairs, const float* __restrict__ memory,
    const float* __restrict__ w1g, const float* __restrict__ w2g,
    const float* __restrict__ wihg, const float* __restrict__ whhg,
    const float* __restrict__ lw1g,
    const float* __restrict__ b1, const float* __restrict__ b2,
    const float* __restrict__ bih, const float* __restrict__ bhh,
    const float* __restrict__ lb1, const float* __restrict__ lw2,
    const float* __restrict__ lb2, float* __restrict__ out)
{
    __shared__ __align__(16) char wlds[WLDS_BYTES];  // all 5 weight tiles, swizzled
    __shared__ __align__(16) char work[6][12288];    // per-wave: tileA 6K + tileB 6K

    const int tid = threadIdx.x;
    const int w  = tid >> 6;
    const int l  = tid & 63;
    const int lr = l & 15;       // M/N index within fragment
    const int lg = l >> 4;       // k-group / row-group

    // ---- stage weights once: f32 global -> bf16 LDS (swizzled) ----
    for (int c = tid; c < NCHUNK; c += 384) {
        int byte = c * 16;
        int e    = c * 8;
        const float* src;
        int base, sh;
        if (e < 8192)       { src = w1g  + e;         base = 0;     sh = 8; }
        else if (e < 12288) { src = w2g  + e - 8192;  base = 16384; sh = 7; }
        else if (e < 24576) { src = wihg + e - 12288; base = 24576; sh = 7; }
        else if (e < 36864) { src = whhg + e - 24576; base = 49152; sh = 7; }
        else                { src = lw1g + e - 36864; base = 73728; sh = 8; }
        f32x4 v0 = *(const f32x4*)src;
        f32x4 v1 = *(const f32x4*)(src + 4);
        union { unsigned u[4]; short8 s; } r;
        r.u[0] = cvtpk(v0[0], v0[1]); r.u[1] = cvtpk(v0[2], v0[3]);
        r.u[2] = cvtpk(v1[0], v1[1]); r.u[3] = cvtpk(v1[2], v1[3]);
        int t   = byte - base;
        int row = t >> sh;
        int dst = base + (t ^ ((row & 7) << 4));
        *(short8*)(wlds + dst) = r.s;
    }
    __syncthreads();   // weights visible to all waves (only block barrier)

    char* n1A = &work[w][0];      // tile A: n1 -> c1
    char* n2A = &work[w][2048];   //         n2 -> c2
    char* hmA = &work[w][4096];   //         h1 -> msg
    char* n1B = &work[w][6144];   // tile B
    char* n2B = &work[w][8192];
    char* hmB = &work[w][10240];

    const char* w1l  = wlds + 0;      // [64][128] s256
    const char* w2l  = wlds + 16384;  // [64][64]  s128
    const char* wihl = wlds + 24576;  // [192][64] s128
    const char* whhl = wlds + 49152;  // [192][64] s128
    const char* lw1l = wlds + 73728;  // [64][128] s256

    const f32x4 z4 = {0.0f, 0.0f, 0.0f, 0.0f};

    const int stid = blockIdx.x * 6 + w;   // supertile id, 0..1535; 8192 total

    // pairs prefetch for both tiles: 8x int2 = 16 VGPRs
    int2 prA[4], prB[4];
#pragma unroll
    for (int rr = 0; rr < 4; ++rr) {
        prA[rr] = *(const int2*)(pairs + (stid * 32 + rr * 4 + lg) * 2);
        prB[rr] = *(const int2*)(pairs + (stid * 32 + 16 + rr * 4 + lg) * 2);
    }

#pragma unroll 1   // one body copy: I$-hot across iterations
    for (int st = stid; st < 8192; st += 1536) {
        const int r0 = st * 32;

        // ---- stage 0: gather rows for BOTH tiles -> bf16 LDS ----
#pragma unroll
        for (int rr = 0; rr < 4; ++rr) {
            int row = rr * 4 + lg;
            f32x4 vA1 = *(const f32x4*)(memory + (long)prA[rr].x * 64 + lr * 4);
            f32x4 vA2 = *(const f32x4*)(memory + (long)prA[rr].y * 64 + lr * 4);
            f32x4 vB1 = *(const f32x4*)(memory + (long)prB[rr].x * 64 + lr * 4);
            f32x4 vB2 = *(const f32x4*)(memory + (long)prB[rr].y * 64 + lr * 4);
            uint2 cA1, cA2, cB1, cB2;
            cA1.x = cvtpk(vA1[0], vA1[1]); cA1.y = cvtpk(vA1[2], vA1[3]);
            cA2.x = cvtpk(vA2[0], vA2[1]); cA2.y = cvtpk(vA2[2], vA2[3]);
            cB1.x = cvtpk(vB1[0], vB1[1]); cB1.y = cvtpk(vB1[2], vB1[3]);
            cB2.x = cvtpk(vB2[0], vB2[1]); cB2.y = cvtpk(vB2[2], vB2[3]);
            int off = sw128(row, lr * 8);
            *(uint2*)(n1A + off) = cA1;
            *(uint2*)(n2A + off) = cA2;
            *(uint2*)(n1B + off) = cB1;
            *(uint2*)(n2B + off) = cB2;
        }
        // prefetch next supertile's pairs (uniform branch)
        {
            int next = st + 1536;
            if (next < 8192) {
#pragma unroll
                for (int rr = 0; rr < 4; ++rr) {
                    prA[rr] = *(const int2*)(pairs + (next * 32 + rr * 4 + lg) * 2);
                    prB[rr] = *(const int2*)(pairs + (next * 32 + 16 + rr * 4 + lg) * 2);
                }
            }
        }
        WAVE_FENCE();

        // ---- stage 1: H1 = relu(X @ w1^T + b1) for both tiles (shared B) ----
        f32x4 accA[4], accB[4];
#pragma unroll
        for (int nt = 0; nt < 4; ++nt) { accA[nt] = z4; accB[nt] = z4; }
#pragma unroll
        for (int kt = 0; kt < 4; ++kt) {
            const char* baA = (kt < 2) ? n1A : n2A;
            const char* baB = (kt < 2) ? n1B : n2B;
            int ao = sw128(lr, (kt & 1) * 64 + lg * 16);
            short8 aA = *(const short8*)(baA + ao);
            short8 aB = *(const short8*)(baB + ao);
#pragma unroll
            for (int nt = 0; nt < 4; ++nt) {
                short8 b = *(const short8*)(w1l + sw256(nt * 16 + lr, kt * 64 + lg * 16));
                accA[nt] = __builtin_amdgcn_mfma_f32_16x16x32_bf16(aA, b, accA[nt], 0, 0, 0);
                accB[nt] = __builtin_amdgcn_mfma_f32_16x16x32_bf16(aB, b, accB[nt], 0, 0, 0);
            }
        }
#pragma unroll
        for (int nt = 0; nt < 4; ++nt) {
            float bv = b1[nt * 16 + lr];
            unsigned a01 = cvtpk(fmaxf(accA[nt][0] + bv, 0.0f), fmaxf(accA[nt][1] + bv, 0.0f));
            unsigned a23 = cvtpk(fmaxf(accA[nt][2] + bv, 0.0f), fmaxf(accA[nt][3] + bv, 0.0f));
            unsigned b01 = cvtpk(fmaxf(accB[nt][0] + bv, 0.0f), fmaxf(accB[nt][1] + bv, 0.0f));
            unsigned b23 = cvtpk(fmaxf(accB[nt][2] + bv, 0.0f), fmaxf(accB[nt][3] + bv, 0.0f));
            int cb = nt * 32 + lr * 2;
            *(short*)(hmA + sw128(lg * 4 + 0, cb)) = (short)a01;
            *(short*)(hmA + sw128(lg * 4 + 1, cb)) = (short)(a01 >> 16);
            *(short*)(hmA + sw128(lg * 4 + 2, cb)) = (short)a23;
            *(short*)(hmA + sw128(lg * 4 + 3, cb)) = (short)(a23 >> 16);
            *(short*)(hmB + sw128(lg * 4 + 0, cb)) = (short)b01;
            *(short*)(hmB + sw128(lg * 4 + 1, cb)) = (short)(b01 >> 16);
            *(short*)(hmB + sw128(lg * 4 + 2, cb)) = (short)b23;
            *(short*)(hmB + sw128(lg * 4 + 3, cb)) = (short)(b23 >> 16);
        }
        WAVE_FENCE();

        // ---- stage 2: MSG = H1 @ w2^T + b2 (shared B); msg overlays h1 ----
#pragma unroll
        for (int nt = 0; nt < 4; ++nt) { accA[nt] = z4; accB[nt] = z4; }
#pragma unroll
        for (int kt = 0; kt < 2; ++kt) {
            int ao = sw128(lr, kt * 64 + lg * 16);
            short8 aA = *(const short8*)(hmA + ao);
            short8 aB = *(const short8*)(hmB + ao);
#pragma unroll
            for (int nt = 0; nt < 4; ++nt) {
                short8 b = *(const short8*)(w2l + sw128(nt * 16 + lr, kt * 64 + lg * 16));
                accA[nt] = __builtin_amdgcn_mfma_f32_16x16x32_bf16(aA, b, accA[nt], 0, 0, 0);
                accB[nt] = __builtin_amdgcn_mfma_f32_16x16x32_bf16(aB, b, accB[nt], 0, 0, 0);
            }
        }
#pragma unroll
        for (int nt = 0; nt < 4; ++nt) {
            float bv = b2[nt * 16 + lr];
            unsigned a01 = cvtpk(accA[nt][0] + bv, accA[nt][1] + bv);
            unsigned a23 = cvtpk(accA[nt][2] + bv, accA[nt][3] + bv);
            unsigned b01 = cvtpk(accB[nt][0] + bv, accB[nt][1] + bv);
            unsigned b23 = cvtpk(accB[nt][2] + bv, accB[nt][3] + bv);
            int cb = nt * 32 + lr * 2;
            *(short*)(hmA + sw128(lg * 4 + 0, cb)) = (short)a01;
            *(short*)(hmA + sw128(lg * 4 + 1, cb)) = (short)(a01 >> 16);
            *(short*)(hmA + sw128(lg * 4 + 2, cb)) = (short)a23;
            *(short*)(hmA + sw128(lg * 4 + 3, cb)) = (short)(a23 >> 16);
            *(short*)(hmB + sw128(lg * 4 + 0, cb)) = (short)b01;
            *(short*)(hmB + sw128(lg * 4 + 1, cb)) = (short)(b01 >> 16);
            *(short*)(hmB + sw128(lg * 4 + 2, cb)) = (short)b23;
            *(short*)(hmB + sw128(lg * 4 + 3, cb)) = (short)(b23 >> 16);
        }
        WAVE_FENCE();

        // ---- stage 3+4: gates (shared B-frags, 2x MFMA) + GRU per tile ----
        short8 amA[2], amB[2], a1A[2], a1B[2], a2A[2], a2B[2];
#pragma unroll
        for (int kt = 0; kt < 2; ++kt) {
            int ao = sw128(lr, kt * 64 + lg * 16);
            amA[kt] = *(const short8*)(hmA + ao);
            amB[kt] = *(const short8*)(hmB + ao);
            a1A[kt] = *(const short8*)(n1A + ao);
            a1B[kt] = *(const short8*)(n1B + ao);
            a2A[kt] = *(const short8*)(n2A + ao);
            a2B[kt] = *(const short8*)(n2B + ao);
        }
#pragma unroll
        for (int nt = 0; nt < 4; ++nt) {
            f32x4 girA = z4, gizA = z4, ginA = z4;
            f32x4 g1rA = z4, g1zA = z4, g1nA = z4;
            f32x4 g2rA = z4, g2zA = z4, g2nA = z4;
            f32x4 girB = z4, gizB = z4, ginB = z4;
            f32x4 g1rB = z4, g1zB = z4, g1nB = z4;
            f32x4 g2rB = z4, g2zB = z4, g2nB = z4;
#pragma unroll
            for (int kt = 0; kt < 2; ++kt) {
                int ko = kt * 64 + lg * 16;
                short8 bir = *(const short8*)(wihl + sw128((0 + nt) * 16 + lr, ko));
                short8 biz = *(const short8*)(wihl + sw128((4 + nt) * 16 + lr, ko));
                short8 bin = *(const short8*)(wihl + sw128((8 + nt) * 16 + lr, ko));
                short8 bhr = *(const short8*)(whhl + sw128((0 + nt) * 16 + lr, ko));
                short8 bhz = *(const short8*)(whhl + sw128((4 + nt) * 16 + lr, ko));
                short8 bhn = *(const short8*)(whhl + sw128((8 + nt) * 16 + lr, ko));
                girA = __builtin_amdgcn_mfma_f32_16x16x32_bf16(amA[kt], bir, girA, 0, 0, 0);
                girB = __builtin_amdgcn_mfma_f32_16x16x32_bf16(amB[kt], bir, girB, 0, 0, 0);
                gizA = __builtin_amdgcn_mfma_f32_16x16x32_bf16(amA[kt], biz, gizA, 0, 0, 0);
                gizB = __builtin_amdgcn_mfma_f32_16x16x32_bf16(amB[kt], biz, gizB, 0, 0, 0);
                ginA = __builtin_amdgcn_mfma_f32_16x16x32_bf16(amA[kt], bin, ginA, 0, 0, 0);
                ginB = __builtin_amdgcn_mfma_f32_16x16x32_bf16(amB[kt], bin, ginB, 0, 0, 0);
                g1rA = __builtin_amdgcn_mfma_f32_16x16x32_bf16(a1A[kt], bhr, g1rA, 0, 0, 0);
                g1rB = __builtin_amdgcn_mfma_f32_16x16x32_bf16(a1B[kt], bhr, g1rB, 0, 0, 0);
                g1zA = __builtin_amdgcn_mfma_f32_16x16x32_bf16(a1A[kt], bhz, g1zA, 0, 0, 0);
                g1zB = __builtin_amdgcn_mfma_f32_16x16x32_bf16(a1B[kt], bhz, g1zB, 0, 0, 0);
                g1nA = __builtin_amdgcn_mfma_f32_16x16x32_bf16(a1A[kt], bhn, g1nA, 0, 0, 0);
                g1nB = __builtin_amdgcn_mfma_f32_16x16x32_bf16(a1B[kt], bhn, g1nB, 0, 0, 0);
                g2rA = __builtin_amdgcn_mfma_f32_16x16x32_bf16(a2A[kt], bhr, g2rA, 0, 0, 0);
                g2rB = __builtin_amdgcn_mfma_f32_16x16x32_bf16(a2B[kt], bhr, g2rB, 0, 0, 0);
                g2zA = __builtin_amdgcn_mfma_f32_16x16x32_bf16(a2A[kt], bhz, g2zA, 0, 0, 0);
                g2zB = __builtin_amdgcn_mfma_f32_16x16x32_bf16(a2B[kt], bhz, g2zB, 0, 0, 0);
                g2nA = __builtin_amdgcn_mfma_f32_16x16x32_bf16(a2A[kt], bhn, g2nA, 0, 0, 0);
                g2nB = __builtin_amdgcn_mfma_f32_16x16x32_bf16(a2B[kt], bhn, g2nB, 0, 0, 0);
            }
            int j = nt * 16 + lr;
            float bir_ = bih[j], biz_ = bih[64 + j], bin_ = bih[128 + j];
            float bhr_ = bhh[j], bhz_ = bhh[64 + j], bhn_ = bhh[128 + j];
            // tile A GRU + comb write
            {
                float o1[4], o2[4];
#pragma unroll
                for (int r = 0; r < 4; ++r) {
                    int row = lg * 4 + r;
                    float i_r = girA[r] + bir_;
                    float i_z = gizA[r] + biz_;
                    float i_n = ginA[r] + bin_;
                    float rg = sigm(i_r + g1rA[r] + bhr_);
                    float zg = sigm(i_z + g1zA[r] + bhz_);
                    float ng = tanh_f(i_n + rg * (g1nA[r] + bhn_));
                    float h  = b2f(*(const short*)(n1A + sw128(row, j * 2)));
                    o1[r] = (1.0f - zg) * ng + zg * h;
                    rg = sigm(i_r + g2rA[r] + bhr_);
                    zg = sigm(i_z + g2zA[r] + bhz_);
                    ng = tanh_f(i_n + rg * (g2nA[r] + bhn_));
                    h  = b2f(*(const short*)(n2A + sw128(row, j * 2)));
                    o2[r] = (1.0f - zg) * ng + zg * h;
                }
                unsigned q01 = cvtpk(o1[0], o1[1]), q23 = cvtpk(o1[2], o1[3]);
                unsigned s01 = cvtpk(o2[0], o2[1]), s23 = cvtpk(o2[2], o2[3]);
                *(short*)(n1A + sw128(lg * 4 + 0, j * 2)) = (short)q01;
                *(short*)(n1A + sw128(lg * 4 + 1, j * 2)) = (short)(q01 >> 16);
                *(short*)(n1A + sw128(lg * 4 + 2, j * 2)) = (short)q23;
                *(short*)(n1A + sw128(lg * 4 + 3, j * 2)) = (short)(q23 >> 16);
                *(short*)(n2A + sw128(lg * 4 + 0, j * 2)) = (short)s01;
                *(short*)(n2A + sw128(lg * 4 + 1, j * 2)) = (short)(s01 >> 16);
                *(short*)(n2A + sw128(lg * 4 + 2, j * 2)) = (short)s23;
                *(short*)(n2A + sw128(lg * 4 + 3, j * 2)) = (short)(s23 >> 16);
            }
            // tile B GRU + comb write
            {
                float o1[4], o2[4];
#pragma unroll
                for (int r = 0; r < 4; ++r) {
                    int row = lg * 4 + r;
                    float i_r = girB[r] + bir_;
                    float i_z = gizB[r] + biz_;
                    float i_n = ginB[r] + bin_;
                    float rg = sigm(i_r + g1rB[r] + bhr_);
                    float zg = sigm(i_z + g1zB[r] + bhz_);
                    float ng = tanh_f(i_n + rg * (g1nB[r] + bhn_));
                    float h  = b2f(*(const short*)(n1B + sw128(row, j * 2)));
                    o1[r] = (1.0f - zg) * ng + zg * h;
                    rg = sigm(i_r + g2rB[r] + bhr_);
                    zg = sigm(i_z + g2zB[r] + bhz_);
                    ng = tanh_f(i_n + rg * (g2nB[r] + bhn_));
                    h  = b2f(*(const short*)(n2B + sw128(row, j * 2)));
                    o2[r] = (1.0f - zg) * ng + zg * h;
                }
                unsigned q01 = cvtpk(o1[0], o1[1]), q23 = cvtpk(o1[2], o1[3]);
                unsigned s01 = cvtpk(o2[0], o2[1]), s23 = cvtpk(o2[2], o2[3]);
                *(short*)(n1B + sw128(lg * 4 + 0, j * 2)) = (short)q01;
                *(short*)(n1B + sw128(lg * 4 + 1, j * 2)) = (short)(q01 >> 16);
                *(short*)(n1B + sw128(lg * 4 + 2, j * 2)) = (short)q23;
                *(short*)(n1B + sw128(lg * 4 + 3, j * 2)) = (short)(q23 >> 16);
                *(short*)(n2B + sw128(lg * 4 + 0, j * 2)) = (short)s01;
                *(short*)(n2B + sw128(lg * 4 + 1, j * 2)) = (short)(s01 >> 16);
                *(short*)(n2B + sw128(lg * 4 + 2, j * 2)) = (short)s23;
                *(short*)(n2B + sw128(lg * 4 + 3, j * 2)) = (short)(s23 >> 16);
            }
        }
        WAVE_FENCE();

        // ---- stage 5: H = relu(COMB @ lp_w1^T + lb1), both tiles (shared B) ----
        f32x4 acc5A[4], acc5B[4];
#pragma unroll
        for (int nt = 0; nt < 4; ++nt) { acc5A[nt] = z4; acc5B[nt] = z4; }
#pragma unroll
        for (int kt = 0; kt < 4; ++kt) {
            const char* baA = (kt < 2) ? n1A : n2A;
            const char* baB = (kt < 2) ? n1B : n2B;
            int ao = sw128(lr, (kt & 1) * 64 + lg * 16);
            short8 aA = *(const short8*)(baA + ao);
            short8 aB = *(const short8*)(baB + ao);
#pragma unroll
            for (int nt = 0; nt < 4; ++nt) {
                short8 b = *(const short8*)(lw1l + sw256(nt * 16 + lr, kt * 64 + lg * 16));
                acc5A[nt] = __builtin_amdgcn_mfma_f32_16x16x32_bf16(aA, b, acc5A[nt], 0, 0, 0);
                acc5B[nt] = __builtin_amdgcn_mfma_f32_16x16x32_bf16(aB, b, acc5B[nt], 0, 0, 0);
            }
        }

        // ---- stage 6: out = sigmoid(H @ lp_w2^T + lb2), both tiles ----
        float partA[4] = {0.0f, 0.0f, 0.0f, 0.0f};
        float partB[4] = {0.0f, 0.0f, 0.0f, 0.0f};
#pragma unroll
        for (int nt = 0; nt < 4; ++nt) {
            float w2v = lw2[nt * 16 + lr];
            float bv  = lb1[nt * 16 + lr];
#pragma unroll
            for (int r = 0; r < 4; ++r) {
                partA[r] += fmaxf(acc5A[nt][r] + bv, 0.0f) * w2v;
                partB[r] += fmaxf(acc5B[nt][r] + bv, 0.0f) * w2v;
            }
        }
        float lb2v = lb2[0];
#pragma unroll
        for (int r = 0; r < 4; ++r) {
            float pA = partA[r], pB = partB[r];
            pA += __shfl_xor(pA, 1); pB += __shfl_xor(pB, 1);
            pA += __shfl_xor(pA, 2); pB += __shfl_xor(pB, 2);
            pA += __shfl_xor(pA, 4); pB += __shfl_xor(pB, 4);
            pA += __shfl_xor(pA, 8); pB += __shfl_xor(pB, 8);
            if (lr == 0) {
                out[r0 + lg * 4 + r]      = sigm(pA + lb2v);
                out[r0 + 16 + lg * 4 + r] = sigm(pB + lb2v);
            }
        }
        // loop-top LDS writes are WAR-safe vs stage-5 reads: DS in-order per wave.
    }
}

extern "C" void kernel_launch(void* const* d_in, const int* in_sizes, int n_in,
                              void* d_out, int out_size, void* d_ws, size_t ws_size,
                              hipStream_t stream) {
    const int*   pairs  = (const int*)d_in[0];
    const float* memory = (const float*)d_in[1];
    const float* w1  = (const float*)d_in[2];
    const float* b1  = (const float*)d_in[3];
    const float* w2  = (const float*)d_in[4];
    const float* b2  = (const float*)d_in[5];
    const float* wih = (const float*)d_in[6];
    const float* whh = (const float*)d_in[7];
    const float* bih = (const float*)d_in[8];
    const float* bhh = (const float*)d_in[9];
    const float* lw1 = (const float*)d_in[10];
    const float* lb1 = (const float*)d_in[11];
    const float* lw2 = (const float*)d_in[12];
    const float* lb2 = (const float*)d_in[13];

    // persistent: 256 blocks (1/CU), 6 waves each, 32 rows/wave, grid-stride
    tgn_kernel<<<256, 384, 0, stream>>>(pairs, memory, w1, w2, wih, whh, lw1,
                                        b1, b2, bih, bhh, lb1, lw2, lb2,
                                        (float*)d_out);
}

// Round 22
// 105.373 us; speedup vs baseline: 1.2854x; 1.2854x over previous
//
#include <hip/hip_runtime.h>

#define BATCH 262144

typedef __attribute__((ext_vector_type(8))) short short8;
typedef __attribute__((ext_vector_type(4))) float f32x4;

static __device__ __forceinline__ unsigned cvtpk(float lo, float hi) {
    unsigned r;
    asm("v_cvt_pk_bf16_f32 %0, %1, %2" : "=v"(r) : "v"(lo), "v"(hi));
    return r;
}
static __device__ __forceinline__ float b2f(short s) {
    return __uint_as_float(((unsigned)(unsigned short)s) << 16);
}
static __device__ __forceinline__ float sigm(float x) { return 1.0f / (1.0f + __expf(-x)); }
static __device__ __forceinline__ float tanh_f(float x) { return 1.0f - 2.0f / (__expf(2.0f * x) + 1.0f); }

// LDS serves a wave's DS ops in program order; compiler-only barrier keeps
// instruction order (R15: verified correct, neutral vs lgkmcnt(0) drain).
#define WAVE_FENCE() asm volatile("" ::: "memory")

// XOR swizzle on 16B slots within a row (R4/R10-validated, <=2-way aliasing).
static __device__ __forceinline__ int sw128(int row, int cb) { return row * 128 + (cb ^ ((row & 7) << 4)); }
static __device__ __forceinline__ int sw256(int row, int cb) { return row * 256 + (cb ^ ((row & 7) << 4)); }

// Weight LDS (swizzled): w1 @0 [64][128]s256, w2 @16384 [64][64]s128,
// wih @24576 [192][64]s128, whh @49152 [192][64]s128, lw1 @73728 [64][128]s256
#define WLDS_BYTES 90112
#define NCHUNK (WLDS_BYTES / 16)

// FINAL (R20 config, session best 105.6 us):
// 768 threads = 12 waves; LDS 90112 + 12*6144 = 163840 B = full 160 KiB pool
// -> 1 block/CU, 3 waves/SIMD. Plain launch bounds (no-spill).
// PERSISTENT grid=256: weights staged once/CU; pairs-only prefetch (8 VGPR).
// Bracketing evidence: 16 waves (R11/R18/R19) and 6 waves x M=32 (R21) both
// regress; reg row-prefetch spills (R13/R16); s_setprio null (R17);
// s_barrier null/harmful (R8/R11). Weights converted f32->bf16 during
// staging (prep kernel deleted, R20 win).
__global__ __launch_bounds__(768) void tgn_kernel(
    const int* __restrict__ pairs, const float* __restrict__ memory,
    const float* __restrict__ w1g, const float* __restrict__ w2g,
    const float* __restrict__ wihg, const float* __restrict__ whhg,
    const float* __restrict__ lw1g,
    const float* __restrict__ b1, const float* __restrict__ b2,
    const float* __restrict__ bih, const float* __restrict__ bhh,
    const float* __restrict__ lb1, const float* __restrict__ lw2,
    const float* __restrict__ lb2, float* __restrict__ out)
{
    __shared__ __align__(16) char wlds[WLDS_BYTES];  // all 5 weight tiles, swizzled
    __shared__ __align__(16) char work[12][6144];    // per-wave: n1(2K) n2(2K) h1==msg(2K)

    const int tid = threadIdx.x;
    const int w  = tid >> 6;
    const int l  = tid & 63;
    const int lr = l & 15;       // M/N index within fragment
    const int lg = l >> 4;       // k-group / row-group

    // ---- stage weights once: f32 global -> bf16 LDS (swizzled), 8 elems/chunk.
    for (int c = tid; c < NCHUNK; c += 768) {
        int byte = c * 16;       // bf16 byte offset in wlds layout
        int e    = c * 8;        // bf16 element index
        const float* src;
        int base, sh;
        if (e < 8192)       { src = w1g  + e;         base = 0;     sh = 8; }
        else if (e < 12288) { src = w2g  + e - 8192;  base = 16384; sh = 7; }
        else if (e < 24576) { src = wihg + e - 12288; base = 24576; sh = 7; }
        else if (e < 36864) { src = whhg + e - 24576; base = 49152; sh = 7; }
        else                { src = lw1g + e - 36864; base = 73728; sh = 8; }
        f32x4 v0 = *(const f32x4*)src;
        f32x4 v1 = *(const f32x4*)(src + 4);
        union { unsigned u[4]; short8 s; } r;
        r.u[0] = cvtpk(v0[0], v0[1]); r.u[1] = cvtpk(v0[2], v0[3]);
        r.u[2] = cvtpk(v1[0], v1[1]); r.u[3] = cvtpk(v1[2], v1[3]);
        int t   = byte - base;
        int row = t >> sh;
        int dst = base + (t ^ ((row & 7) << 4));
        *(short8*)(wlds + dst) = r.s;
    }
    __syncthreads();   // weights visible to all waves (only block barrier)

    char* n1b = &work[w][0];     // [16][64] bf16 sw128; later comb c1 overlay
    char* n2b = &work[w][2048];  // [16][64] bf16 sw128; later comb c2 overlay
    char* hmb = &work[w][4096];  // h1, then msg (stage-2 reads precede writes)

    const char* w1l  = wlds + 0;      // [64][128] s256
    const char* w2l  = wlds + 16384;  // [64][64]  s128
    const char* wihl = wlds + 24576;  // [192][64] s128
    const char* whhl = wlds + 49152;  // [192][64] s128
    const char* lw1l = wlds + 73728;  // [64][128] s256

    const f32x4 z4 = {0.0f, 0.0f, 0.0f, 0.0f};

    const int waveid = blockIdx.x * 12 + w;   // 0..3071

    // pairs prefetch: 4x int2 = 8 VGPRs live across the body (NOT row data)
    int2 pr[4];
#pragma unroll
    for (int rr = 0; rr < 4; ++rr)
        pr[rr] = *(const int2*)(pairs + (waveid * 16 + rr * 4 + lg) * 2);

#pragma unroll 1   // one body copy: I$-hot across iterations
    for (int tile = waveid; tile < 16384; tile += 3072) {
        const int r0 = tile * 16;

        // ---- stage 0: gather rows (pairs already resident) -> bf16 LDS ----
#pragma unroll
        for (int rr = 0; rr < 4; ++rr) {
            int row = rr * 4 + lg;
            f32x4 v1 = *(const f32x4*)(memory + (long)pr[rr].x * 64 + lr * 4);
            f32x4 v2 = *(const f32x4*)(memory + (long)pr[rr].y * 64 + lr * 4);
            uint2 c1v, c2v;
            c1v.x = cvtpk(v1[0], v1[1]); c1v.y = cvtpk(v1[2], v1[3]);
            c2v.x = cvtpk(v2[0], v2[1]); c2v.y = cvtpk(v2[2], v2[3]);
            int off = sw128(row, lr * 8);
            *(uint2*)(n1b + off) = c1v;
            *(uint2*)(n2b + off) = c2v;
        }
        // prefetch next tile's pairs (uniform branch)
        {
            int next = tile + 3072;
            if (next < 16384) {
#pragma unroll
                for (int rr = 0; rr < 4; ++rr)
                    pr[rr] = *(const int2*)(pairs + (next * 16 + rr * 4 + lg) * 2);
            }
        }
        WAVE_FENCE();

        // ---- stage 1: H1 = relu(X @ w1^T + b1), X = [n1|n2] (16x128) ----
        f32x4 acc[4];
#pragma unroll
        for (int nt = 0; nt < 4; ++nt) acc[nt] = z4;
#pragma unroll
        for (int kt = 0; kt < 4; ++kt) {
            const char* base = (kt < 2) ? n1b : n2b;
            short8 a = *(const short8*)(base + sw128(lr, (kt & 1) * 64 + lg * 16));
#pragma unroll
            for (int nt = 0; nt < 4; ++nt) {
                short8 b = *(const short8*)(w1l + sw256(nt * 16 + lr, kt * 64 + lg * 16));
                acc[nt] = __builtin_amdgcn_mfma_f32_16x16x32_bf16(a, b, acc[nt], 0, 0, 0);
            }
        }
#pragma unroll
        for (int nt = 0; nt < 4; ++nt) {
            float bv = b1[nt * 16 + lr];
            unsigned p01 = cvtpk(fmaxf(acc[nt][0] + bv, 0.0f), fmaxf(acc[nt][1] + bv, 0.0f));
            unsigned p23 = cvtpk(fmaxf(acc[nt][2] + bv, 0.0f), fmaxf(acc[nt][3] + bv, 0.0f));
            int cb = nt * 32 + lr * 2;
            *(short*)(hmb + sw128(lg * 4 + 0, cb)) = (short)p01;
            *(short*)(hmb + sw128(lg * 4 + 1, cb)) = (short)(p01 >> 16);
            *(short*)(hmb + sw128(lg * 4 + 2, cb)) = (short)p23;
            *(short*)(hmb + sw128(lg * 4 + 3, cb)) = (short)(p23 >> 16);
        }
        WAVE_FENCE();

        // ---- stage 2: MSG = H1 @ w2^T + b2; msg overlays h1 ----
#pragma unroll
        for (int nt = 0; nt < 4; ++nt) acc[nt] = z4;
#pragma unroll
        for (int kt = 0; kt < 2; ++kt) {
            short8 a = *(const short8*)(hmb + sw128(lr, kt * 64 + lg * 16));
#pragma unroll
            for (int nt = 0; nt < 4; ++nt) {
                short8 b = *(const short8*)(w2l + sw128(nt * 16 + lr, kt * 64 + lg * 16));
                acc[nt] = __builtin_amdgcn_mfma_f32_16x16x32_bf16(a, b, acc[nt], 0, 0, 0);
            }
        }
#pragma unroll
        for (int nt = 0; nt < 4; ++nt) {
            float bv = b2[nt * 16 + lr];
            unsigned p01 = cvtpk(acc[nt][0] + bv, acc[nt][1] + bv);
            unsigned p23 = cvtpk(acc[nt][2] + bv, acc[nt][3] + bv);
            int cb = nt * 32 + lr * 2;
            *(short*)(hmb + sw128(lg * 4 + 0, cb)) = (short)p01;
            *(short*)(hmb + sw128(lg * 4 + 1, cb)) = (short)(p01 >> 16);
            *(short*)(hmb + sw128(lg * 4 + 2, cb)) = (short)p23;
            *(short*)(hmb + sw128(lg * 4 + 3, cb)) = (short)(p23 >> 16);
        }
        WAVE_FENCE();

        // ---- stage 3+4 fused: gates (LDS weights) + GRU; comb overlays n1/n2 ----
        short8 am[2], a1[2], a2[2];
#pragma unroll
        for (int kt = 0; kt < 2; ++kt) {
            am[kt] = *(const short8*)(hmb + sw128(lr, kt * 64 + lg * 16));
            a1[kt] = *(const short8*)(n1b + sw128(lr, kt * 64 + lg * 16));
            a2[kt] = *(const short8*)(n2b + sw128(lr, kt * 64 + lg * 16));
        }
#pragma unroll
        for (int nt = 0; nt < 4; ++nt) {
            f32x4 gir = z4, giz = z4, gin = z4;
            f32x4 g1r = z4, g1z = z4, g1n = z4;
            f32x4 g2r = z4, g2z = z4, g2n = z4;
#pragma unroll
            for (int kt = 0; kt < 2; ++kt) {
                int ko = kt * 64 + lg * 16;
                short8 bir = *(const short8*)(wihl + sw128((0 + nt) * 16 + lr, ko));
                short8 biz = *(const short8*)(wihl + sw128((4 + nt) * 16 + lr, ko));
                short8 bin = *(const short8*)(wihl + sw128((8 + nt) * 16 + lr, ko));
                short8 bhr = *(const short8*)(whhl + sw128((0 + nt) * 16 + lr, ko));
                short8 bhz = *(const short8*)(whhl + sw128((4 + nt) * 16 + lr, ko));
                short8 bhn = *(const short8*)(whhl + sw128((8 + nt) * 16 + lr, ko));
                gir = __builtin_amdgcn_mfma_f32_16x16x32_bf16(am[kt], bir, gir, 0, 0, 0);
                giz = __builtin_amdgcn_mfma_f32_16x16x32_bf16(am[kt], biz, giz, 0, 0, 0);
                gin = __builtin_amdgcn_mfma_f32_16x16x32_bf16(am[kt], bin, gin, 0, 0, 0);
                g1r = __builtin_amdgcn_mfma_f32_16x16x32_bf16(a1[kt], bhr, g1r, 0, 0, 0);
                g1z = __builtin_amdgcn_mfma_f32_16x16x32_bf16(a1[kt], bhz, g1z, 0, 0, 0);
                g1n = __builtin_amdgcn_mfma_f32_16x16x32_bf16(a1[kt], bhn, g1n, 0, 0, 0);
                g2r = __builtin_amdgcn_mfma_f32_16x16x32_bf16(a2[kt], bhr, g2r, 0, 0, 0);
                g2z = __builtin_amdgcn_mfma_f32_16x16x32_bf16(a2[kt], bhz, g2z, 0, 0, 0);
                g2n = __builtin_amdgcn_mfma_f32_16x16x32_bf16(a2[kt], bhn, g2n, 0, 0, 0);
            }
            int j = nt * 16 + lr;
            float bir_ = bih[j], biz_ = bih[64 + j], bin_ = bih[128 + j];
            float bhr_ = bhh[j], bhz_ = bhh[64 + j], bhn_ = bhh[128 + j];
            float o1[4], o2[4];
#pragma unroll
            for (int r = 0; r < 4; ++r) {
                int row = lg * 4 + r;
                float i_r = gir[r] + bir_;
                float i_z = giz[r] + biz_;
                float i_n = gin[r] + bin_;
                float rg = sigm(i_r + g1r[r] + bhr_);
                float zg = sigm(i_z + g1z[r] + bhz_);
                float ng = tanh_f(i_n + rg * (g1n[r] + bhn_));
                float h  = b2f(*(const short*)(n1b + sw128(row, j * 2)));
                o1[r] = (1.0f - zg) * ng + zg * h;
                rg = sigm(i_r + g2r[r] + bhr_);
                zg = sigm(i_z + g2z[r] + bhz_);
                ng = tanh_f(i_n + rg * (g2n[r] + bhn_));
                h  = b2f(*(const short*)(n2b + sw128(row, j * 2)));
                o2[r] = (1.0f - zg) * ng + zg * h;
            }
            unsigned q01 = cvtpk(o1[0], o1[1]), q23 = cvtpk(o1[2], o1[3]);
            unsigned s01 = cvtpk(o2[0], o2[1]), s23 = cvtpk(o2[2], o2[3]);
            *(short*)(n1b + sw128(lg * 4 + 0, j * 2)) = (short)q01;
            *(short*)(n1b + sw128(lg * 4 + 1, j * 2)) = (short)(q01 >> 16);
            *(short*)(n1b + sw128(lg * 4 + 2, j * 2)) = (short)q23;
            *(short*)(n1b + sw128(lg * 4 + 3, j * 2)) = (short)(q23 >> 16);
            *(short*)(n2b + sw128(lg * 4 + 0, j * 2)) = (short)s01;
            *(short*)(n2b + sw128(lg * 4 + 1, j * 2)) = (short)(s01 >> 16);
            *(short*)(n2b + sw128(lg * 4 + 2, j * 2)) = (short)s23;
            *(short*)(n2b + sw128(lg * 4 + 3, j * 2)) = (short)(s23 >> 16);
        }
        WAVE_FENCE();

        // ---- stage 5: H = relu(COMB @ lp_w1^T + lb1); comb = [c1|c2] ----
        f32x4 acc5[4];
#pragma unroll
        for (int nt = 0; nt < 4; ++nt) acc5[nt] = z4;
#pragma unroll
        for (int kt = 0; kt < 4; ++kt) {
            const char* base = (kt < 2) ? n1b : n2b;
            short8 a = *(const short8*)(base + sw128(lr, (kt & 1) * 64 + lg * 16));
#pragma unroll
            for (int nt = 0; nt < 4; ++nt) {
                short8 b = *(const short8*)(lw1l + sw256(nt * 16 + lr, kt * 64 + lg * 16));
                acc5[nt] = __builtin_amdgcn_mfma_f32_16x16x32_bf16(a, b, acc5[nt], 0, 0, 0);
            }
        }

        // ---- stage 6: out = sigmoid(H @ lp_w2^T + lb2), reduce over 64 cols ----
        float part[4] = {0.0f, 0.0f, 0.0f, 0.0f};
#pragma unroll
        for (int nt = 0; nt < 4; ++nt) {
            float w2v = lw2[nt * 16 + lr];
            float bv  = lb1[nt * 16 + lr];
#pragma unroll
            for (int r = 0; r < 4; ++r)
                part[r] += fmaxf(acc5[nt][r] + bv, 0.0f) * w2v;
        }
        float lb2v = lb2[0];
#pragma unroll
        for (int r = 0; r < 4; ++r) {
            float p = part[r];
            p += __shfl_xor(p, 1);
            p += __shfl_xor(p, 2);
            p += __shfl_xor(p, 4);
            p += __shfl_xor(p, 8);
            if (lr == 0) out[r0 + lg * 4 + r] = sigm(p + lb2v);
        }
        // loop-top LDS writes are WAR-safe vs stage-5 reads: DS in-order per wave.
    }
}

extern "C" void kernel_launch(void* const* d_in, const int* in_sizes, int n_in,
                              void* d_out, int out_size, void* d_ws, size_t ws_size,
                              hipStream_t stream) {
    const int*   pairs  = (const int*)d_in[0];
    const float* memory = (const float*)d_in[1];
    const float* w1  = (const float*)d_in[2];
    const float* b1  = (const float*)d_in[3];
    const float* w2  = (const float*)d_in[4];
    const float* b2  = (const float*)d_in[5];
    const float* wih = (const float*)d_in[6];
    const float* whh = (const float*)d_in[7];
    const float* bih = (const float*)d_in[8];
    const float* bhh = (const float*)d_in[9];
    const float* lw1 = (const float*)d_in[10];
    const float* lb1 = (const float*)d_in[11];
    const float* lw2 = (const float*)d_in[12];
    const float* lb2 = (const float*)d_in[13];

    // single kernel: weights converted f32->bf16 during per-block LDS staging
    tgn_kernel<<<256, 768, 0, stream>>>(pairs, memory, w1, w2, wih, whh, lw1,
                                        b1, b2, bih, bhh, lb1, lw2, lb2,
                                        (float*)d_out);
}